// Round 3
// baseline (95.567 us; speedup 1.0000x reference)
//
#include <hip/hip_runtime.h>

#define KCODES 512
#define DIM    64
#define NVEC   65536          // 64 * 32 * 32
#define TAU    0.05f          // near-tie trigger in dist/2 units (fp32 err ~2e-4)

typedef __attribute__((ext_vector_type(8))) short   short8;  // 8 bf16 = 4 VGPRs
typedef __attribute__((ext_vector_type(4))) float   f32x4;

static __device__ __forceinline__ unsigned f2bfu(float f) {  // fp32 -> bf16 RNE
    unsigned u = __builtin_bit_cast(unsigned, f);
    u += 0x7fffu + ((u >> 16) & 1u);
    return u >> 16;
}

// async global -> LDS, 16 B per lane. LDS dest must be wave-uniform base;
// HW writes base + lane*16. Global src is per-lane.
static __device__ __forceinline__ void glds16(const unsigned short* g,
                                              unsigned short* l) {
    __builtin_amdgcn_global_load_lds(
        (const __attribute__((address_space(1))) unsigned int*)g,
        (__attribute__((address_space(3))) unsigned int*)l, 16, 0, 0);
}

// ---------------------------------------------------------------------------
// Prep (single dispatch, 640 blocks x 64 thr):
//  blocks 0..127  : rearrange codebook into staged-tile layout cbt.
//    granule g (16 B = 8 bf16) for g = s*1024 + h*512 + qd*64 + cl holds
//    codebook[s*64+cl][qd*8 .. qd*8+8) (h=0: bf16-hi trunc, h=1: bf16-lo RNE).
//  blocks 128..639: e2q[k] = ||e_k||^2/2 + 256 (fp64 reduce).
// ---------------------------------------------------------------------------
__global__ void prep_kernel(const float* __restrict__ cb,
                            unsigned short* __restrict__ cbt,
                            float* __restrict__ e2q) {
    if (blockIdx.x < 128) {
        const int g   = blockIdx.x * 64 + threadIdx.x;   // 0..8191
        const int s   = g >> 10;
        const int rem = g & 1023;
        const int h   = rem >> 9;
        const int qd  = (rem >> 6) & 7;
        const int cl  = rem & 63;
        const float* src = cb + (size_t)(s * 64 + cl) * DIM + qd * 8;
        short8 v;
#pragma unroll
        for (int j = 0; j < 8; ++j) {
            float f = src[j];
            unsigned u = __builtin_bit_cast(unsigned, f);
            if (h == 0) {
                v[j] = (short)(u >> 16);
            } else {
                float hi = __builtin_bit_cast(float, u & 0xFFFF0000u);
                v[j] = (short)f2bfu(f - hi);
            }
        }
        *(short8*)(cbt + (size_t)g * 8) = v;
    } else {
        const int k = blockIdx.x - 128;                  // 0..511
        float v = cb[k * DIM + threadIdx.x];
        double p = (double)v * (double)v;
#pragma unroll
        for (int off = 32; off > 0; off >>= 1) p += __shfl_down(p, off, 64);
        if (threadIdx.x == 0) e2q[k] = (float)(0.5 * p + 256.0);
    }
}

// ---------------------------------------------------------------------------
// Main: block = 256 thr / 64 vectors, 4 waves. ZERO barriers in the main
// loop: wave (wr,wc) owns 32 vectors (B in 32 VGPR) x 256 codes and stages
// its 16-code tile (4 KB) per step into its OWN private 8 KB LDS double
// buffer via 4x global_load_lds. Per-wave counted s_waitcnt vmcnt(4)
// (depth-2 pipeline) replaces __syncthreads -- waves free-run, so the
// per-step barrier-drain stall (the dominant cost of the 90 us baseline:
// issue model says ~6 us/CU, measured ~41 us) disappears. Buffer overwrite
// is safe by program order: stage(sp+2) into buf[sp&1] is issued only after
// step sp's ds_reads were consumed; the async LDS write lands >=300 cyc
// later. cbt re-read 4x per block is L2-resident. LDS 34.8 KB -> 4
// blocks/CU, 16 waves/CU. Numerics unchanged: acc init = e2/2+256, B = -x
// (rank-safe), exact fp32 top-2 w/ index, fp64 re-resolve on near-tie.
// ---------------------------------------------------------------------------
__launch_bounds__(256, 4)
__global__ void vq_main(const float* __restrict__ x,
                        const float* __restrict__ cb,
                        const unsigned short* __restrict__ cbt,
                        const float* __restrict__ e2q,
                        float* __restrict__ out) {
    __shared__ __align__(16) unsigned short sPriv[4][4096]; // 32 KB: 4 x (2x4KB)
    __shared__ float sE2[KCODES];

    // lifetime 1 (prologue): B-exchange buffer aliases sPriv[0..1]
    unsigned short* sB = &sPriv[0][0];
    // lifetime 2 (epilogue, after post-loop barrier): merge scratch
    unsigned char* scr = (unsigned char*)&sPriv[0][0];
    float* s_pf1 = (float*)(scr);           // [64][2]
    float* s_pf2 = (float*)(scr + 512);     // [64][2]
    int*   s_pi1 = (int*)(scr + 1024);      // [64][2]
    int*   s_pi2 = (int*)(scr + 1536);      // [64][2]
    int*   s_i1  = (int*)(scr + 2048);      // [64]
    int*   s_i2  = (int*)(scr + 2304);      // [64]
    int*   s_flag= (int*)(scr + 2560);      // [64]
    int*   s_win = (int*)(scr + 2816);      // [64]

    const int tid  = threadIdx.x;
    const int wave = tid >> 6;
    const int lane = tid & 63;
    const int quad = lane >> 4;
    const int l16  = lane & 15;
    const int wr   = wave >> 1;   // vector-half: n-tiles {2wr, 2wr+1}
    const int wc   = wave & 1;    // code-half: codes [wc*256, wc*256+256)

    const int v0    = blockIdx.x * 64;
    const int b     = v0 >> 10;
    const int nbase = v0 & 1023;
    const float* xb = x + (size_t)b * 65536;

    // ---- build OWN n-tile (= wave) B fragments of NEGATED x -> sB ----------
    // granule = tile*256 + h*128 + ko*64 + lane (16 B each)
    {
        const int n_g = nbase + wave * 16 + l16;
#pragma unroll
        for (int ko = 0; ko < 2; ++ko) {
            short8 bh, bl;
#pragma unroll
            for (int j = 0; j < 8; ++j) {
                const int d = quad * 8 + j + ko * 32;
                float f = -xb[(size_t)d * 1024 + n_g];
                unsigned u = __builtin_bit_cast(unsigned, f);
                float hi = __builtin_bit_cast(float, u & 0xFFFF0000u);
                bh[j] = (short)(u >> 16);
                bl[j] = (short)f2bfu(f - hi);
            }
            *(short8*)(sB + (size_t)(wave * 256 +       ko * 64 + lane) * 8) = bh;
            *(short8*)(sB + (size_t)(wave * 256 + 128 + ko * 64 + lane) * 8) = bl;
        }
    }

    if (tid < 128) *(f32x4*)(sE2 + tid * 4) = *(const f32x4*)(e2q + tid * 4);
    __syncthreads();   // sB + sE2 visible

    // ---- read back B for this wave's 2 n-tiles (32 VGPR, one-time) ---------
    short8 Bh[2][2], Bl[2][2];
#pragma unroll
    for (int t = 0; t < 2; ++t) {
        const int tile = 2 * wr + t;
#pragma unroll
        for (int ko = 0; ko < 2; ++ko) {
            Bh[t][ko] = *(const short8*)(sB + (size_t)(tile * 256 +       ko * 64 + lane) * 8);
            Bl[t][ko] = *(const short8*)(sB + (size_t)(tile * 256 + 128 + ko * 64 + lane) * 8);
        }
    }
    __syncthreads();   // all B reads done; sPriv free for private staging

    // ---- per-wave private staging (NO cross-wave sync from here to loop end)
    unsigned short* wbuf = &sPriv[wave][0];          // 2 x 2048 shorts
    const int glb = (lane >> 4) * 64 + (lane & 15);  // per-lane granule base

    // 16-code tile for step sp: codes wc*256 + sp*16 + [0,16).
    // cbt granule = S*1024 + h*512 + qd*64 + cl; S = wc*4 + (sp>>2),
    // cl = (sp&3)*16 + l16. Op i: h = i>>1, qd = (i&1)*4 + quad
    //   -> src granule = base + i*256 + glb ; dest = wbuf + hsel*2048 + i*512
    // A-read back: A00/A01/A10/A11 at granule k*64 + lane (k = 0..3).
#define STAGE(sp_)                                                            \
    {                                                                         \
        const int sb_ = wc * 4096 + ((sp_) >> 2) * 1024 + ((sp_) & 3) * 16 + glb; \
        unsigned short* d_ = wbuf + ((sp_) & 1) * 2048;                       \
        _Pragma("unroll")                                                     \
        for (int i_ = 0; i_ < 4; ++i_)                                        \
            glds16(cbt + (size_t)(sb_ + i_ * 256) * 8, d_ + i_ * 512);        \
    }

    STAGE(0)
    STAGE(1)

    float f1[2] = {1e30f, 1e30f}, f2_[2] = {1e30f, 1e30f};
    int   i1[2] = {0, 0},         i2_[2] = {0, 0};

#pragma unroll 1
    for (int sp = 0; sp < 16; ++sp) {
        // wait for tile sp (the 4 newest loads -- tile sp+1 -- may stay in flight)
        if (sp < 15) { asm volatile("s_waitcnt vmcnt(4)" ::: "memory"); }
        else         { asm volatile("s_waitcnt vmcnt(0)" ::: "memory"); }

        const unsigned short* buf = wbuf + (sp & 1) * 2048;
        short8 A00 = *(const short8*)(buf + (size_t)(       lane) * 8); // hi,o0
        short8 A01 = *(const short8*)(buf + (size_t)( 64 + lane) * 8);  // hi,o1
        short8 A10 = *(const short8*)(buf + (size_t)(128 + lane) * 8);  // lo,o0
        short8 A11 = *(const short8*)(buf + (size_t)(192 + lane) * 8);  // lo,o1
        const int cbase = wc * 256 + sp * 16;
        const int idb   = cbase + quad * 4;
        f32x4 e2v = *(const f32x4*)(sE2 + idb);

#pragma unroll
        for (int t = 0; t < 2; ++t) {
            f32x4 acc = e2v;   // = e2/2 + 256; with B = -x: rank-safe dist
            acc = __builtin_amdgcn_mfma_f32_16x16x32_bf16(A00, Bh[t][0], acc, 0, 0, 0);
            acc = __builtin_amdgcn_mfma_f32_16x16x32_bf16(A01, Bh[t][1], acc, 0, 0, 0);
            acc = __builtin_amdgcn_mfma_f32_16x16x32_bf16(A00, Bl[t][0], acc, 0, 0, 0);
            acc = __builtin_amdgcn_mfma_f32_16x16x32_bf16(A01, Bl[t][1], acc, 0, 0, 0);
            acc = __builtin_amdgcn_mfma_f32_16x16x32_bf16(A10, Bh[t][0], acc, 0, 0, 0);
            acc = __builtin_amdgcn_mfma_f32_16x16x32_bf16(A11, Bh[t][1], acc, 0, 0, 0);

#pragma unroll
            for (int r = 0; r < 4; ++r) {
                float dd = acc[r];
                int   id = idb + r;
                bool  c1 = dd < f1[t];               // strict: earlier id wins
                bool  c2 = dd < f2_[t];
                i2_[t] = c1 ? i1[t] : (c2 ? id : i2_[t]);
                f2_[t] = fminf(fmaxf(f1[t], dd), f2_[t]);  // med3
                i1[t]  = c1 ? id : i1[t];
                f1[t]  = fminf(f1[t], dd);
            }
        }

        // issue tile sp+2 into the buffer just consumed (write lands late;
        // reads above already completed -- program order + sched fence)
        __builtin_amdgcn_sched_barrier(0);
        if (sp < 14) STAGE(sp + 2)
    }

    __syncthreads();   // all waves out of their private buffers -> scratch ok

    // ---- cross-quad butterfly per n-tile (lanes {c,c+16,..} same vector) ---
#pragma unroll
    for (int t = 0; t < 2; ++t) {
        float F1 = f1[t], F2 = f2_[t];
        int   I1 = i1[t], I2 = i2_[t];
#pragma unroll
        for (int delta = 16; delta <= 32; delta <<= 1) {
            float of1 = __shfl_xor(F1, delta, 64);
            int   oi1 = __shfl_xor(I1, delta, 64);
            float of2 = __shfl_xor(F2, delta, 64);
            int   oi2 = __shfl_xor(I2, delta, 64);
            bool o1_first = (of1 < F1) || (of1 == F1 && oi1 < I1);
            if (o1_first) {
                bool keep = (F1 < of2) || (F1 == of2 && I1 < oi2);
                F2 = keep ? F1 : of2;
                I2 = keep ? I1 : oi2;
                F1 = of1; I1 = oi1;
            } else {
                bool o1_second = (of1 < F2) || (of1 == F2 && oi1 < I2);
                if (o1_second) { F2 = of1; I2 = oi1; }
            }
        }
        if (quad == 0) {   // lanes 0..15: per-code-half partial for vector v
            const int v = wr * 32 + t * 16 + l16;
            s_pf1[v * 2 + wc] = F1;
            s_pf2[v * 2 + wc] = F2;
            s_pi1[v * 2 + wc] = I1;
            s_pi2[v * 2 + wc] = I2;
        }
    }
    __syncthreads();

    // ---- cross-wave top-2 merge (64 threads, one per vector) ---------------
    if (tid < 64) {
        const int v = tid;
        float F1 = s_pf1[v * 2 + 0], F2 = s_pf2[v * 2 + 0];
        int   I1 = s_pi1[v * 2 + 0], I2 = s_pi2[v * 2 + 0];
        {
            float of1 = s_pf1[v * 2 + 1], of2 = s_pf2[v * 2 + 1];
            int   oi1 = s_pi1[v * 2 + 1], oi2 = s_pi2[v * 2 + 1];
            bool o1_first = (of1 < F1) || (of1 == F1 && oi1 < I1);
            if (o1_first) {
                bool keep = (F1 < of2) || (F1 == of2 && I1 < oi2);
                F2 = keep ? F1 : of2;
                I2 = keep ? I1 : oi2;
                F1 = of1; I1 = oi1;
            } else {
                bool o1_second = (of1 < F2) || (of1 == F2 && oi1 < I2);
                if (o1_second) { F2 = of1; I2 = oi1; }
            }
        }
        s_win[v]  = I1;
        s_i1[v]   = I1;
        s_i2[v]   = I2;
        s_flag[v] = (F2 - F1) < TAU;
    }
    __syncthreads();

    // ---- parallel fp64 re-resolve: 4 lanes per vector, both candidates -----
    {
        const int vec = tid >> 2, sub = tid & 3;   // 64 vectors x 4 lanes
        if (s_flag[vec]) {
            const int i1c = s_i1[vec], i2c = s_i2[vec];
            const float* xr = xb + nbase + vec;
            const float* r1 = cb + (size_t)i1c * DIM;
            const float* r2 = cb + (size_t)i2c * DIM;
            double D1 = 0.0, D2 = 0.0;
#pragma unroll 4
            for (int i = 0; i < 16; ++i) {
                const int d = sub + 4 * i;
                double xd = (double)xr[(size_t)d * 1024];
                double t1 = xd - (double)r1[d]; D1 += t1 * t1;
                double t2 = xd - (double)r2[d]; D2 += t2 * t2;
            }
            D1 += __shfl_down(D1, 2, 64); D1 += __shfl_down(D1, 1, 64);
            D2 += __shfl_down(D2, 2, 64); D2 += __shfl_down(D2, 1, 64);
            if (sub == 0) {
                if (D2 < D1 || (D2 == D1 && i2c < i1c)) s_win[vec] = i2c;
            }
        }
    }
    __syncthreads();

    // ---- output: out[b, d, nbase+n] = cb[win[n]][d], coalesced over n ------
    {
        const int n    = tid & 63;            // 64 vectors
        const int dgrp = tid >> 6;            // 4 groups of 16 dims
        const float4* crow = (const float4*)(cb + (size_t)s_win[n] * DIM);
        float* op = out + (size_t)b * 65536 + nbase + n;
#pragma unroll
        for (int i = 0; i < 4; ++i) {
            const int d0 = dgrp * 16 + i * 4;
            float4 val = crow[d0 >> 2];
            op[(size_t)(d0 + 0) * 1024] = val.x;
            op[(size_t)(d0 + 1) * 1024] = val.y;
            op[(size_t)(d0 + 2) * 1024] = val.z;
            op[(size_t)(d0 + 3) * 1024] = val.w;
        }
    }
}

extern "C" void kernel_launch(void* const* d_in, const int* in_sizes, int n_in,
                              void* d_out, int out_size, void* d_ws, size_t ws_size,
                              hipStream_t stream) {
    const float* x  = (const float*)d_in[0];   // (64, 64, 32, 32) fp32
    const float* cb = (const float*)d_in[1];   // (512, 64) fp32
    float* out = (float*)d_out;

    // workspace: cbt (128 KB staged-tile codebook) | e2q (2 KB)
    unsigned short* cbt = (unsigned short*)d_ws;
    float*          e2q = (float*)(cbt + 8192 * 8);

    prep_kernel<<<640, 64, 0, stream>>>(cb, cbt, e2q);
    vq_main<<<NVEC / 64, 256, 0, stream>>>(x, cb, cbt, e2q, out);
}

// Round 5
// 90.762 us; speedup vs baseline: 1.0529x; 1.0529x over previous
//
#include <hip/hip_runtime.h>

#define KCODES 512
#define DIM    64
#define NVEC   65536          // 64 * 32 * 32
#define TAU    0.05f          // near-tie trigger in dist/2 units (fp32 err ~2e-4)

typedef __attribute__((ext_vector_type(8))) short   short8;  // 8 bf16 = 4 VGPRs
typedef __attribute__((ext_vector_type(4))) float   f32x4;

static __device__ __forceinline__ unsigned f2bfu(float f) {  // fp32 -> bf16 RNE
    unsigned u = __builtin_bit_cast(unsigned, f);
    u += 0x7fffu + ((u >> 16) & 1u);
    return u >> 16;
}

// async global -> LDS, 16 B per lane. LDS dest must be wave-uniform base;
// HW writes base + lane*16. Global src is per-lane.
static __device__ __forceinline__ void glds16(const unsigned short* g,
                                              unsigned short* l) {
    __builtin_amdgcn_global_load_lds(
        (const __attribute__((address_space(1))) unsigned int*)g,
        (__attribute__((address_space(3))) unsigned int*)l, 16, 0, 0);
}

// ---------------------------------------------------------------------------
// Prep (single dispatch, 640 blocks x 64 thr):
//  blocks 0..127  : rearrange codebook into staged-tile layout cbt.
//    granule g (16 B = 8 bf16) for g = s*1024 + h*512 + qd*64 + cl holds
//    codebook[s*64+cl][qd*8 .. qd*8+8) (h=0: bf16-hi trunc, h=1: bf16-lo RNE).
//    This makes the main kernel's LDS staging a LINEAR copy (no conflicts),
//    and lets staging go through global_load_lds (wave-uniform dest).
//  blocks 128..639: e2q[k] = ||e_k||^2/2 + 256 (fp64 reduce).
// ---------------------------------------------------------------------------
__global__ void prep_kernel(const float* __restrict__ cb,
                            unsigned short* __restrict__ cbt,
                            float* __restrict__ e2q) {
    if (blockIdx.x < 128) {
        const int g   = blockIdx.x * 64 + threadIdx.x;   // 0..8191
        const int s   = g >> 10;
        const int rem = g & 1023;
        const int h   = rem >> 9;
        const int qd  = (rem >> 6) & 7;
        const int cl  = rem & 63;
        const float* src = cb + (size_t)(s * 64 + cl) * DIM + qd * 8;
        short8 v;
#pragma unroll
        for (int j = 0; j < 8; ++j) {
            float f = src[j];
            unsigned u = __builtin_bit_cast(unsigned, f);
            if (h == 0) {
                v[j] = (short)(u >> 16);
            } else {
                float hi = __builtin_bit_cast(float, u & 0xFFFF0000u);
                v[j] = (short)f2bfu(f - hi);
            }
        }
        *(short8*)(cbt + (size_t)g * 8) = v;
    } else {
        const int k = blockIdx.x - 128;                  // 0..511
        float v = cb[k * DIM + threadIdx.x];
        double p = (double)v * (double)v;
#pragma unroll
        for (int off = 32; off > 0; off >>= 1) p += __shfl_down(p, off, 64);
        if (threadIdx.x == 0) e2q[k] = (float)(0.5 * p + 256.0);
    }
}

// ---------------------------------------------------------------------------
// Main: round-0 champion structure (89.7 us) with ONE change: staging goes
// through global_load_lds width-16 (pattern hardware-proven in the round-2
// variant, which passed refcheck with identical granule indices and barrier
// placement). Removes per step/wave: 4 global_load_dwordx4, 4 ds_write_b128,
// 16 stg VGPRs. Selection/merge/re-resolve/output are verbatim round 0
// (the round-4 med3 asm is condemned and reverted).
// Block = 256 thr / 64 vectors, 4 waves; wave w ranks ALL 512 codes for its
// 16 vectors. Grid = 1024 -> 4 blocks/CU (LDS 34.2 KB), 16 waves/CU.
// Numerics: acc init = e2/2+256, B = -x => rank-safe dist; exact fp32 top-2
// w/ index; fp64 re-resolve of both candidates on near-tie.
// ---------------------------------------------------------------------------
__launch_bounds__(256, 4)
__global__ void vq_main(const float* __restrict__ x,
                        const float* __restrict__ cb,
                        const unsigned short* __restrict__ cbt,
                        const float* __restrict__ e2q,
                        float* __restrict__ out) {
    __shared__ __align__(16) unsigned short sA[2][8192];   // 16 KB per buffer
    __shared__ float sE2[KCODES];
    __shared__ int   s_i1[64], s_i2[64], s_flag[64], s_win[64];

    const int tid  = threadIdx.x;
    const int wave = tid >> 6;
    const int lane = tid & 63;
    const int quad = lane >> 4;
    const int l16  = lane & 15;

    const int v0    = blockIdx.x * 64;
    const int b     = v0 >> 10;
    const int nbase = v0 & 1023;
    const float* xb = x + (size_t)b * 65536;

    // ---- stage step 0 via global_load_lds (latency hidden by B build) ------
#pragma unroll
    for (int r = 0; r < 4; ++r)
        glds16(cbt + (size_t)(wave * 64 + r * 256 + lane) * 8,
               sA[0] + (size_t)(wave * 64 + r * 256) * 8);

    // ---- B fragments of NEGATED x: B[k=quad*8+j+32ko][n=l16], hi/lo --------
    short8 Bh[2], Bl[2];
    {
        const int n_g = nbase + wave * 16 + l16;
#pragma unroll
        for (int ko = 0; ko < 2; ++ko) {
#pragma unroll
            for (int j = 0; j < 8; ++j) {
                const int d = quad * 8 + j + ko * 32;
                float f = -xb[(size_t)d * 1024 + n_g];
                unsigned u = __builtin_bit_cast(unsigned, f);
                float hi = __builtin_bit_cast(float, u & 0xFFFF0000u);
                Bh[ko][j] = (short)(u >> 16);
                Bl[ko][j] = (short)f2bfu(f - hi);
            }
        }
    }

    // ---- stage e2 into LDS -------------------------------------------------
    if (tid < 128) *(f32x4*)(sE2 + tid * 4) = *(const f32x4*)(e2q + tid * 4);
    __syncthreads();   // drains vmcnt (step 0 staged) + lgkm (sE2 visible)

    float f1 = 1e30f, f2_ = 1e30f;
    int   i1 = 0,     i2_ = 0;

#pragma unroll 1
    for (int s = 0; s < 8; ++s) {
        // issue next-step staging early (flies during compute; the end-of-step
        // barrier drains vmcnt). Target buffer's readers finished last step.
        if (s < 7) {
#pragma unroll
            for (int r = 0; r < 4; ++r)
                glds16(cbt + (size_t)((s + 1) * 1024 + wave * 64 + r * 256 + lane) * 8,
                       sA[(s + 1) & 1] + (size_t)(wave * 64 + r * 256) * 8);
        }

        const unsigned short* buf = sA[s & 1];
#pragma unroll
        for (int st = 0; st < 4; ++st) {
            const int cbase = s * 64 + st * 16;
            const int roff  = quad * 64 + st * 16 + l16;   // lane-contiguous
            short8 A00 = *(const short8*)(buf + (size_t)(      roff) * 8); // hi,o0
            short8 A01 = *(const short8*)(buf + (size_t)(256 + roff) * 8); // hi,o1
            short8 A10 = *(const short8*)(buf + (size_t)(512 + roff) * 8); // lo,o0
            short8 A11 = *(const short8*)(buf + (size_t)(768 + roff) * 8); // lo,o1
            f32x4  e2v = *(const f32x4*)(sE2 + cbase + quad * 4);

            f32x4 acc = e2v;   // = e2/2 + 256; with B = -x: rank-safe dist
            acc = __builtin_amdgcn_mfma_f32_16x16x32_bf16(A00, Bh[0], acc, 0, 0, 0);
            acc = __builtin_amdgcn_mfma_f32_16x16x32_bf16(A01, Bh[1], acc, 0, 0, 0);
            acc = __builtin_amdgcn_mfma_f32_16x16x32_bf16(A00, Bl[0], acc, 0, 0, 0);
            acc = __builtin_amdgcn_mfma_f32_16x16x32_bf16(A01, Bl[1], acc, 0, 0, 0);
            acc = __builtin_amdgcn_mfma_f32_16x16x32_bf16(A10, Bh[0], acc, 0, 0, 0);
            acc = __builtin_amdgcn_mfma_f32_16x16x32_bf16(A11, Bh[1], acc, 0, 0, 0);

#pragma unroll
            for (int r = 0; r < 4; ++r) {
                float dd = acc[r];
                int   id = cbase + quad * 4 + r;
                bool  c1 = dd < f1;               // strict: earlier id wins
                bool  c2 = dd < f2_;
                i2_ = c1 ? i1 : (c2 ? id : i2_);
                f2_ = fminf(fmaxf(f1, dd), f2_);  // med3(f1, dd, f2)
                i1  = c1 ? id : i1;
                f1  = fminf(f1, dd);
            }
        }
        __syncthreads();
    }

    // ---- cross-quad butterfly merge (lanes {c,c+16,c+32,c+48} same vecs) ---
    {
#pragma unroll
        for (int delta = 16; delta <= 32; delta <<= 1) {
            float of1 = __shfl_xor(f1, delta, 64);
            int   oi1 = __shfl_xor(i1, delta, 64);
            float of2 = __shfl_xor(f2_, delta, 64);
            int   oi2 = __shfl_xor(i2_, delta, 64);
            bool o1_first = (of1 < f1) || (of1 == f1 && oi1 < i1);
            if (o1_first) {
                bool keep = (f1 < of2) || (f1 == of2 && i1 < oi2);
                f2_ = keep ? f1 : of2;
                i2_ = keep ? i1 : oi2;
                f1 = of1; i1 = oi1;
            } else {
                bool o1_second = (of1 < f2_) || (of1 == f2_ && oi1 < i2_);
                if (o1_second) { f2_ = of1; i2_ = oi1; }
            }
        }
        if (quad == 0) {   // lanes 0..15 hold final result for their vector
            const int vl = wave * 16 + l16;
            s_win[vl]  = i1;
            s_i1[vl]   = i1;
            s_i2[vl]   = i2_;
            s_flag[vl] = (f2_ - f1) < TAU;
        }
    }
    __syncthreads();

    // ---- parallel fp64 re-resolve: 4 lanes per vector, both candidates -----
    {
        const int vec = tid >> 2, sub = tid & 3;   // 64 vectors x 4 lanes
        if (s_flag[vec]) {
            const int i1c = s_i1[vec], i2c = s_i2[vec];
            const float* xr = xb + nbase + vec;
            const float* r1 = cb + (size_t)i1c * DIM;
            const float* r2 = cb + (size_t)i2c * DIM;
            double D1 = 0.0, D2 = 0.0;
#pragma unroll 4
            for (int i = 0; i < 16; ++i) {
                const int d = sub + 4 * i;
                double xd = (double)xr[(size_t)d * 1024];
                double t1 = xd - (double)r1[d]; D1 += t1 * t1;
                double t2 = xd - (double)r2[d]; D2 += t2 * t2;
            }
            D1 += __shfl_down(D1, 2, 64); D1 += __shfl_down(D1, 1, 64);
            D2 += __shfl_down(D2, 2, 64); D2 += __shfl_down(D2, 1, 64);
            if (sub == 0) {
                if (D2 < D1 || (D2 == D1 && i2c < i1c)) s_win[vec] = i2c;
            }
        }
    }
    __syncthreads();

    // ---- output: out[b, d, nbase+n] = cb[win[n]][d], coalesced over n ------
    {
        const int n    = tid & 63;            // 64 vectors
        const int dgrp = tid >> 6;            // 4 groups of 16 dims
        const float4* crow = (const float4*)(cb + (size_t)s_win[n] * DIM);
        float* op = out + (size_t)b * 65536 + nbase + n;
#pragma unroll
        for (int i = 0; i < 4; ++i) {
            const int d0 = dgrp * 16 + i * 4;
            float4 val = crow[d0 >> 2];
            op[(size_t)(d0 + 0) * 1024] = val.x;
            op[(size_t)(d0 + 1) * 1024] = val.y;
            op[(size_t)(d0 + 2) * 1024] = val.z;
            op[(size_t)(d0 + 3) * 1024] = val.w;
        }
    }
}

extern "C" void kernel_launch(void* const* d_in, const int* in_sizes, int n_in,
                              void* d_out, int out_size, void* d_ws, size_t ws_size,
                              hipStream_t stream) {
    const float* x  = (const float*)d_in[0];   // (64, 64, 32, 32) fp32
    const float* cb = (const float*)d_in[1];   // (512, 64) fp32
    float* out = (float*)d_out;

    // workspace: cbt (128 KB staged-tile codebook) | e2q (2 KB)
    unsigned short* cbt = (unsigned short*)d_ws;
    float*          e2q = (float*)(cbt + 8192 * 8);

    prep_kernel<<<640, 64, 0, stream>>>(cb, cbt, e2q);
    vq_main<<<NVEC / 64, 256, 0, stream>>>(x, cb, cbt, e2q, out);
}